// Round 2
// baseline (1420.490 us; speedup 1.0000x reference)
//
#include <hip/hip_runtime.h>

// IndexedDense: out[b] = relu(x[b] @ ws[idx[b]] + bs[idx[b]])
// B=64, S=512, D=1024, U=4096, E=16.  fp32 in/out, fp16 MFMA internally.

typedef float v4f  __attribute__((ext_vector_type(4)));
typedef _Float16 v8h __attribute__((ext_vector_type(8)));
typedef __fp16  v2fp __attribute__((ext_vector_type(2)));   // cvt_pkrtz return type

constexpr int Bb = 64, Ss = 512, Dd = 1024, Uu = 4096;
constexpr int BM = 128, BN = 128, BK = 32;
constexpr int BKP = 40;            // fp16 LDS row pitch: 80 B -> b128-aligned, uniform banks
constexpr int KT = Dd / BK;        // 32 k-tiles

// Sort batches by expert so consecutive blockIdx.z share the same w panel in L2/LLC.
__global__ void perm_kernel(const int* __restrict__ index, int* __restrict__ perm) {
  const int b = threadIdx.x;        // 64 threads
  const int e = index[b];
  int pos = 0;
  for (int b2 = 0; b2 < Bb; ++b2) {
    const int e2 = index[b2];
    pos += (e2 < e) || (e2 == e && b2 < b);
  }
  perm[pos] = b;
}

__global__ __launch_bounds__(256) void indexed_dense_gemm(
    const float* __restrict__ x, const float* __restrict__ ws,
    const float* __restrict__ bs, const int* __restrict__ index,
    const int* __restrict__ perm, float* __restrict__ out) {
  const int bx = blockIdx.x;          // n-block 0..31
  const int by = blockIdx.y;          // m-block 0..3
  const int bz = perm[blockIdx.z];    // batch, expert-grouped
  const int e  = index[bz];

  const int tid  = threadIdx.x;
  const int lane = tid & 63;
  const int wave = tid >> 6;

  const float* A    = x   + (size_t)bz * (Ss * Dd) + (size_t)(by * BM) * Dd;
  const float* W    = ws  + (size_t)e * (Dd * Uu) + bx * BN;
  const float* bias = bs  + (size_t)e * Uu + bx * BN;
  float*       C    = out + (size_t)bz * (Ss * Uu) + (size_t)(by * BM) * Uu + bx * BN;

  __shared__ __align__(16) _Float16 As[BM * BKP];
  __shared__ __align__(16) _Float16 Bs[BN * BKP];

  // ---- staging assignments ----
  // A: thread t -> row m = t>>1 (0..127), k-halfword k0 = (t&1)*16; 4x float4 global loads
  const int am  = tid >> 1;
  const int ak0 = (tid & 1) * 16;
  const float* Aptr = A + am * Dd + ak0;
  _Float16* aWr = &As[am * BKP + ak0];

  // B: wave w -> n = (w&1)*64 + lane, k rows (w>>1)*16 .. +16; 16 n-coalesced scalar loads
  const int bn  = (wave & 1) * 64 + lane;
  const int bk0 = (wave >> 1) * 16;
  const float* Wptr = W + (size_t)bk0 * Uu + bn;
  _Float16* bWr = &Bs[bn * BKP + bk0];

  // ---- fragment read bases (16x16x32 f16: lane holds 8 k-contiguous) ----
  const int fl = lane & 15;
  const int fq = lane >> 4;           // quad 0..3
  const int wm = (wave >> 1) * 64;
  const int wn = (wave & 1) * 64;
  const _Float16* aRd = &As[(wm + fl) * BKP + fq * 8];
  const _Float16* bRd = &Bs[(wn + fl) * BKP + fq * 8];

  v4f acc[4][4];
  #pragma unroll
  for (int i = 0; i < 4; ++i)
    #pragma unroll
    for (int j = 0; j < 4; ++j) acc[i][j] = {0.f, 0.f, 0.f, 0.f};

  v4f   aReg[4];
  float bReg[16];

  auto loadTile = [&](int kt) {
    const float* p = Aptr + kt * BK;
    #pragma unroll
    for (int i = 0; i < 4; ++i) aReg[i] = ((const v4f*)p)[i];
    const float* q = Wptr + (size_t)kt * (BK * Uu);
    #pragma unroll
    for (int j = 0; j < 16; ++j) bReg[j] = q[(size_t)j * Uu];
  };

  auto stage = [&]() {
    union { v8h v[2]; v2fp h[8]; } ua;
    const float* af = (const float*)aReg;
    #pragma unroll
    for (int i = 0; i < 8; ++i)
      ua.h[i] = __builtin_amdgcn_cvt_pkrtz(af[2 * i], af[2 * i + 1]);
    *(v8h*)(aWr)     = ua.v[0];
    *(v8h*)(aWr + 8) = ua.v[1];

    union { v8h v[2]; v2fp h[8]; } ub;
    #pragma unroll
    for (int i = 0; i < 8; ++i)
      ub.h[i] = __builtin_amdgcn_cvt_pkrtz(bReg[2 * i], bReg[2 * i + 1]);
    *(v8h*)(bWr)     = ub.v[0];
    *(v8h*)(bWr + 8) = ub.v[1];
  };

  // prologue: tile 0
  loadTile(0);
  stage();
  __syncthreads();

  for (int kt = 0; kt < KT; ++kt) {
    if (kt + 1 < KT) loadTile(kt + 1);   // prefetch into regs; vmcnt lands after MFMA

    v8h afr[4], bfr[4];
    #pragma unroll
    for (int mt = 0; mt < 4; ++mt) afr[mt] = *(const v8h*)(aRd + mt * 16 * BKP);
    #pragma unroll
    for (int nt = 0; nt < 4; ++nt) bfr[nt] = *(const v8h*)(bRd + nt * 16 * BKP);

    #pragma unroll
    for (int mt = 0; mt < 4; ++mt)
      #pragma unroll
      for (int nt = 0; nt < 4; ++nt)
        acc[mt][nt] = __builtin_amdgcn_mfma_f32_16x16x32_f16(afr[mt], bfr[nt], acc[mt][nt], 0, 0, 0);

    __syncthreads();                 // all frag reads done before overwrite
    if (kt + 1 < KT) stage();
    __syncthreads();                 // staged tile visible
  }

  // ---- epilogue: bias + relu, C/D layout col=lane&15, row=quad*4+reg ----
  float bv[4];
  #pragma unroll
  for (int nt = 0; nt < 4; ++nt) bv[nt] = bias[wn + nt * 16 + fl];

  const int row0 = wm + fq * 4;
  #pragma unroll
  for (int mt = 0; mt < 4; ++mt) {
    #pragma unroll
    for (int r = 0; r < 4; ++r) {
      float* crow = C + (size_t)(row0 + mt * 16 + r) * Uu + wn + fl;
      #pragma unroll
      for (int nt = 0; nt < 4; ++nt) {
        const float v = acc[mt][nt][r] + bv[nt];
        crow[nt * 16] = fmaxf(v, 0.0f);
      }
    }
  }
}

extern "C" void kernel_launch(void* const* d_in, const int* in_sizes, int n_in,
                              void* d_out, int out_size, void* d_ws, size_t ws_size,
                              hipStream_t stream) {
  const float* x    = (const float*)d_in[0];
  const float* wsP  = (const float*)d_in[1];
  const float* bsP  = (const float*)d_in[2];
  const int*   idx  = (const int*)d_in[3];
  float*       out  = (float*)d_out;
  int*         perm = (int*)d_ws;    // 64 ints — tiny scratch, rewritten every call

  perm_kernel<<<1, 64, 0, stream>>>(idx, perm);
  dim3 grid(Uu / BN, Ss / BM, Bb);
  indexed_dense_gemm<<<grid, 256, 0, stream>>>(x, wsP, bsP, idx, perm, out);
}